// Round 1
// baseline (7820.667 us; speedup 1.0000x reference)
//
#include <hip/hip_runtime.h>
#include <stdint.h>

// Problem dims (fixed)
constexpr int kB   = 64;     // batch
constexpr int kTV  = 40;     // video timesteps
constexpr int kF   = 2048;   // feature dim
constexpr int kH   = 1024;   // hidden
constexpr int kV   = 32000;  // vocab
constexpr int kNS  = 30;     // caption steps
constexpr int kCAP = 31;     // captions length

// ---------------- device helpers ----------------
__device__ __forceinline__ float sigm(float x) { return 1.f / (1.f + __expf(-x)); }
__device__ __forceinline__ float tanh_fast(float x) {
    float e = __expf(2.f * x);
    return 1.f - 2.f / (e + 1.f);   // inf-safe
}
__device__ __forceinline__ unsigned short f2bf(float x) {
    unsigned u = __float_as_uint(x);
    return (unsigned short)((u + 0x7fffu + ((u >> 16) & 1u)) >> 16);  // RNE
}

// ---------------- generic tiled fp32 GEMM ----------------
// C[M,N] = A[M,K] @ B[K,N] (+bias). B is fp32 or bf16 (row-major, ldb=N).
// SPLITK: grid.y = split index, each writes partial C at C + y*M*N (M must be 64... M small).
template <bool BF16B, bool SPLITK>
__global__ __launch_bounds__(256) void gemm_tiled(
    const float* __restrict__ A, const void* __restrict__ Bp,
    float* __restrict__ C, const float* __restrict__ bias,
    int M, int N, int K, int KC)
{
    __shared__ float As[16][64];
    __shared__ float Bs[16][64];
    const int tid = threadIdx.x;
    const int n0 = blockIdx.x * 64;
    int m0, k0, kend;
    if (SPLITK) { m0 = 0; k0 = blockIdx.y * KC; kend = k0 + KC; }
    else        { m0 = blockIdx.y * 64; k0 = 0; kend = K; }

    const int am = tid >> 2, aq = tid & 3;   // A tile load: row am, k-quad aq
    const int bk = tid >> 4, nq = tid & 15;  // B tile load: k-row bk, n-quad nq
    const int tm = tid & 15, tn = tid >> 4;  // micro-tile coords

    const float*          Bf = (const float*)Bp;
    const unsigned short* Bh = (const unsigned short*)Bp;

    float acc[4][4] = {};

    for (int kt = k0; kt < kend; kt += 16) {
        float4 av = *(const float4*)(A + (size_t)(m0 + am) * K + kt + aq * 4);
        float4 bv;
        if (BF16B) {
            ushort4 bh = *(const ushort4*)(Bh + (size_t)(kt + bk) * N + n0 + nq * 4);
            bv.x = __uint_as_float((unsigned)bh.x << 16);
            bv.y = __uint_as_float((unsigned)bh.y << 16);
            bv.z = __uint_as_float((unsigned)bh.z << 16);
            bv.w = __uint_as_float((unsigned)bh.w << 16);
        } else {
            bv = *(const float4*)(Bf + (size_t)(kt + bk) * N + n0 + nq * 4);
        }
        __syncthreads();
        As[aq * 4 + 0][am] = av.x;
        As[aq * 4 + 1][am] = av.y;
        As[aq * 4 + 2][am] = av.z;
        As[aq * 4 + 3][am] = av.w;
        *(float4*)&Bs[bk][nq * 4] = bv;
        __syncthreads();
#pragma unroll
        for (int kk = 0; kk < 16; ++kk) {
            float a[4], b[4];
            *(float4*)a = *(const float4*)&As[kk][tm * 4];
            *(float4*)b = *(const float4*)&Bs[kk][tn * 4];
#pragma unroll
            for (int i = 0; i < 4; ++i)
#pragma unroll
                for (int j = 0; j < 4; ++j) acc[i][j] += a[i] * b[j];
        }
    }

    float* Cout = SPLITK ? (C + (size_t)blockIdx.y * M * N) : C;
    float bj[4] = {0.f, 0.f, 0.f, 0.f};
    if (!SPLITK && bias) {
#pragma unroll
        for (int j = 0; j < 4; ++j) bj[j] = bias[n0 + tn * 4 + j];
    }
#pragma unroll
    for (int i = 0; i < 4; ++i) {
        int row = m0 + tm * 4 + i;
        float4 v;
        v.x = acc[i][0] + bj[0];
        v.y = acc[i][1] + bj[1];
        v.z = acc[i][2] + bj[2];
        v.w = acc[i][3] + bj[3];
        *(float4*)(Cout + (size_t)row * N + n0 + tn * 4) = v;
    }
}

// ---------------- combine split-K partials for feat_h (P3) ----------------
__global__ __launch_bounds__(256) void combine_p3(
    const float* __restrict__ part,   // [4][64][1024]
    const float* __restrict__ bias,   // [1024]
    float* __restrict__ feat_h,       // [64][1024]
    float* __restrict__ xcat1)        // [64][3072], h-slot at +2048
{
    int g = blockIdx.x * 256 + threadIdx.x;  // 0..65535
    int b = g >> 10, n = g & 1023;
    float s = bias[n];
#pragma unroll
    for (int i = 0; i < 4; ++i) s += part[i * 65536 + g];
    feat_h[g] = s;
    xcat1[b * 3072 + 2048 + n] = s;
}

// ---------------- feat mean over TV ----------------
__global__ __launch_bounds__(256) void mean_kernel(
    const float* __restrict__ af, float* __restrict__ fm)
{
    int g = blockIdx.x * 256 + threadIdx.x;  // 64*2048
    int b = g >> 11, f = g & 2047;
    float s = 0.f;
    for (int t = 0; t < kTV; ++t) s += af[((size_t)b * kTV + t) * kF + f];
    fm[g] = s * (1.f / kTV);
}

// ---------------- bias sums + mask sums ----------------
__global__ __launch_bounds__(256) void prep_kernel(
    const float* __restrict__ bih1, const float* __restrict__ bhh1,
    const float* __restrict__ bih2, const float* __restrict__ bhh2,
    const float* __restrict__ capmask,
    float* __restrict__ bsum1, float* __restrict__ bsum2, float* __restrict__ msum)
{
    int g = blockIdx.x * 256 + threadIdx.x;
    if (g < 4096) bsum1[g] = bih1[g] + bhh1[g];
    else if (g < 8192) { int j = g - 4096; bsum2[j] = bih2[j] + bhh2[j]; }
    else if (g < 8192 + kNS) {
        int t = g - 8192;
        float s = 0.f;
        for (int b = 0; b < kB; ++b) s += capmask[b * kCAP + t + 1];
        msum[t] = s;
    }
}

// ---------------- fp32 -> bf16 convert (contiguous) ----------------
__global__ __launch_bounds__(256) void conv_bf16(
    const float* __restrict__ in, unsigned short* __restrict__ out, int n)
{
    int g = blockIdx.x * 256 + threadIdx.x;
    int i = g * 4;
    if (i < n) {
        float4 v = *(const float4*)(in + i);
        ushort4 o;
        o.x = f2bf(v.x); o.y = f2bf(v.y); o.z = f2bf(v.z); o.w = f2bf(v.w);
        *(ushort4*)(out + i) = o;
    }
}

// ---------------- transpose W[No,K] -> out[K,4096] bf16 (No==4096) ----------------
__global__ __launch_bounds__(256) void transp_conv(
    const float* __restrict__ W, unsigned short* __restrict__ out, int K)
{
    __shared__ float t[32][33];
    int k0 = blockIdx.x * 32, j0 = blockIdx.y * 32;
    int tx = threadIdx.x & 31, ty = threadIdx.x >> 5;  // ty 0..7
#pragma unroll
    for (int r = 0; r < 32; r += 8)
        t[ty + r][tx] = W[(size_t)(j0 + ty + r) * K + k0 + tx];
    __syncthreads();
#pragma unroll
    for (int r = 0; r < 32; r += 8)
        out[(size_t)(k0 + ty + r) * 4096 + j0 + tx] = f2bf(t[tx][ty + r]);
}

// ---------------- fused attention per batch row ----------------
__global__ __launch_bounds__(256) void attn_kernel(
    const float* __restrict__ hWaP,   // [4][64][1024] partials
    const float* __restrict__ imgp,   // [B][TV][H]
    const float* __restrict__ vf,     // [B][TV][H]
    const float* __restrict__ attw,   // [H]
    const float* __restrict__ vmask,  // [B][TV]
    const float* __restrict__ Wemb,   // [V][H]
    const int* __restrict__ captions, // [B][CAP]
    int s,
    float* __restrict__ xcat1)        // [B][3072]: [0:1024]=emb, [1024:2048]=atten
{
    __shared__ float hs[kH];
    __shared__ float es[kTV];
    int b = blockIdx.x;
    int tid = threadIdx.x;

    for (int h = tid; h < kH; h += 256) {
        float v = 0.f;
#pragma unroll
        for (int i = 0; i < 4; ++i) v += hWaP[i * 65536 + b * 1024 + h];
        hs[h] = v;
    }
    __syncthreads();

    int wid = tid >> 6, lane = tid & 63;
    for (int t = wid; t < kTV; t += 4) {
        float p = 0.f;
        const float* ip = imgp + ((size_t)b * kTV + t) * kH;
#pragma unroll
        for (int hh = 0; hh < 16; ++hh) {
            int h = hh * 64 + lane;
            float x = hs[h] + ip[h];
            p += tanh_fast(x) * attw[h];
        }
        for (int off = 32; off; off >>= 1) p += __shfl_down(p, off);
        if (lane == 0) es[t] = p;
    }
    __syncthreads();

    // softmax over t (redundant per thread, matches reference exactly)
    float mx = -1e30f;
    for (int t = 0; t < kTV; ++t) mx = fmaxf(mx, es[t]);
    float den = 0.f;
    for (int t = 0; t < kTV; ++t) den += vmask[b * kTV + t] * __expf(es[t] - mx);
    den = den + (den == 0.f ? 1.f : 0.f) + 1e-9f;

    int h0 = tid * 4;
    float4 acc = {0.f, 0.f, 0.f, 0.f};
    for (int t = 0; t < kTV; ++t) {
        float w = vmask[b * kTV + t] * __expf(es[t] - mx) / den;
        float4 v = *(const float4*)(vf + ((size_t)b * kTV + t) * kH + h0);
        acc.x += w * v.x; acc.y += w * v.y; acc.z += w * v.z; acc.w += w * v.w;
    }
    *(float4*)(xcat1 + b * 3072 + 1024 + h0) = acc;

    int word = captions[b * kCAP + s];
    *(float4*)(xcat1 + b * 3072 + h0) = *(const float4*)(Wemb + (size_t)word * kH + h0);
}

// ---------------- LSTM cell update (sums 8 split-K gate partials) ----------------
__global__ __launch_bounds__(256) void cell_kernel(
    const float* __restrict__ gp,    // [8][B][4096]
    const float* __restrict__ bsum,  // [4096]
    float* __restrict__ cbuf,        // [B][1024]
    float* __restrict__ xslot, int ldx, int off,
    float* __restrict__ xslot2, int ldx2, int off2,
    float* __restrict__ h2T)         // optional [H][B]
{
    int g = blockIdx.x * 256 + threadIdx.x;  // 0..65535
    int b = g >> 10, u = g & 1023;
    float gi = bsum[u], gf = bsum[u + 1024], gg = bsum[u + 2048], go = bsum[u + 3072];
#pragma unroll
    for (int s = 0; s < 8; ++s) {
        const float* p = gp + (size_t)s * kB * 4096 + b * 4096;
        gi += p[u]; gf += p[u + 1024]; gg += p[u + 2048]; go += p[u + 3072];
    }
    float i = sigm(gi), f = sigm(gf), gv = tanh_fast(gg), o = sigm(go);
    float c = f * cbuf[g] + i * gv;
    cbuf[g] = c;
    float h = o * tanh_fast(c);
    xslot[b * ldx + off + u] = h;
    if (xslot2) xslot2[b * ldx2 + off2 + u] = h;
    if (h2T) h2T[u * kB + b] = h;
}

// ---------------- logits GEMM: [B,V] = h2[B,H] @ Wv[H,V](bf16), k/b-split ----------------
__global__ __launch_bounds__(256) void logits_kernel(
    const float* __restrict__ h2T,            // [H][B]
    const unsigned short* __restrict__ Wv,    // [H][V] bf16
    float* __restrict__ outp)                 // [2][B][V] partials over k
{
    int tid = threadIdx.x;
    int v0 = blockIdx.x * 512 + tid * 2;
    int b0 = blockIdx.y * 16;
    int k0 = blockIdx.z * 512;
    if (v0 >= kV) return;
    float acc0[16] = {}, acc1[16] = {};
    for (int k = k0; k < k0 + 512; ++k) {
        unsigned w2 = *(const unsigned*)(Wv + (size_t)k * kV + v0);
        float w0 = __uint_as_float(w2 << 16);
        float w1 = __uint_as_float(w2 & 0xffff0000u);
        const float* hp = h2T + k * kB + b0;  // wave-uniform -> scalar loads
#pragma unroll
        for (int bb = 0; bb < 16; ++bb) {
            float h = hp[bb];
            acc0[bb] += w0 * h;
            acc1[bb] += w1 * h;
        }
    }
#pragma unroll
    for (int bb = 0; bb < 16; ++bb) {
        float2 st; st.x = acc0[bb]; st.y = acc1[bb];
        *(float2*)(outp + ((size_t)blockIdx.z * kB + b0 + bb) * kV + v0) = st;
    }
}

// ---------------- per-row log-softmax + CE accumulate ----------------
__global__ __launch_bounds__(256) void loss_kernel(
    const float* __restrict__ lp,    // [2][B][V]
    const float* __restrict__ embb,  // [V]
    const int* __restrict__ captions,
    const float* __restrict__ msum, int s,
    float* __restrict__ out)
{
    int b = blockIdx.x, tid = threadIdx.x;
    const float* p0 = lp + (size_t)b * kV;
    const float* p1 = lp + (size_t)(kB + b) * kV;
    __shared__ float red[4];
    __shared__ float red2[4];

    float mx = -1e30f;
    for (int v = tid; v < kV; v += 256) mx = fmaxf(mx, p0[v] + p1[v] + embb[v]);
    for (int off = 32; off; off >>= 1) mx = fmaxf(mx, __shfl_down(mx, off));
    if ((tid & 63) == 0) red[tid >> 6] = mx;
    __syncthreads();
    mx = fmaxf(fmaxf(red[0], red[1]), fmaxf(red[2], red[3]));

    float sum = 0.f;
    for (int v = tid; v < kV; v += 256) sum += __expf(p0[v] + p1[v] + embb[v] - mx);
    for (int off = 32; off; off >>= 1) sum += __shfl_down(sum, off);
    if ((tid & 63) == 0) red2[tid >> 6] = sum;
    __syncthreads();
    if (tid == 0) {
        float tot = red2[0] + red2[1] + red2[2] + red2[3];
        int tgt = captions[b * kCAP + s + 1];
        float lt = p0[tgt] + p1[tgt] + embb[tgt];
        float logp = lt - mx - __logf(tot);
        atomicAdd(out, -logp * msum[s] * (1.f / (kB * kB)));
    }
}

// ---------------- host ----------------
extern "C" void kernel_launch(void* const* d_in, const int* in_sizes, int n_in,
                              void* d_out, int out_size, void* d_ws, size_t ws_size,
                              hipStream_t stream)
{
    const float* action_feat = (const float*)d_in[1];
    const float* video_mask  = (const float*)d_in[3];
    const int*   captions    = (const int*)d_in[4];
    const float* capmask     = (const float*)d_in[5];
    const float* enc_img_W   = (const float*)d_in[6];
    const float* enc_img_b   = (const float*)d_in[7];
    const float* enc_mean_W  = (const float*)d_in[8];
    const float* enc_mean_b  = (const float*)d_in[9];
    const float* att_w       = (const float*)d_in[10];
    const float* att_Wa      = (const float*)d_in[11];
    const float* att_Ua      = (const float*)d_in[12];
    const float* att_ba      = (const float*)d_in[13];
    const float* Wemb        = (const float*)d_in[14];
    const float* embW        = (const float*)d_in[15];
    const float* embb        = (const float*)d_in[16];
    const float* W1ih        = (const float*)d_in[17];
    const float* W1hh        = (const float*)d_in[18];
    const float* b1ih        = (const float*)d_in[19];
    const float* b1hh        = (const float*)d_in[20];
    const float* W2ih        = (const float*)d_in[21];
    const float* W2hh        = (const float*)d_in[22];
    const float* b2ih        = (const float*)d_in[23];
    const float* b2hh        = (const float*)d_in[24];

    float* w = (float*)d_ws;
    size_t o = 0;
    auto alloc = [&](size_t n) { float* p = w + o; o += (n + 3) & ~(size_t)3; return p; };

    float* vf     = alloc((size_t)2560 * 1024);
    float* imgp   = alloc((size_t)2560 * 1024);
    float* fm     = alloc(64 * 2048);
    float* feat_h = alloc(64 * 1024);
    float* hWaP   = alloc(4 * 64 * 1024);
    float* p3part = alloc(4 * 64 * 1024);
    float* g1p    = alloc((size_t)8 * 64 * 4096);
    float* g2p    = alloc((size_t)8 * 64 * 4096);
    float* logitp = alloc((size_t)2 * 64 * 32000);
    float* xcat1  = alloc(64 * 3072);
    // state block (memset to zero each launch): xcat2, c1, c2 contiguous
    float* xcat2  = alloc(64 * 2048);
    float* c1     = alloc(64 * 1024);
    float* c2     = alloc(64 * 1024);
    float* h2buf  = alloc(64 * 1024);
    float* h2T    = alloc(1024 * 64);
    float* bsum1  = alloc(4096);
    float* bsum2  = alloc(4096);
    float* msum   = alloc(32);
    unsigned short* W1cat = (unsigned short*)(w + o); o += (size_t)3072 * 4096 / 2;
    unsigned short* W2cat = (unsigned short*)(w + o); o += (size_t)2048 * 4096 / 2;
    unsigned short* Wv16  = (unsigned short*)(w + o); o += (size_t)1024 * 32000 / 2;
    if (o * 4 > ws_size) return;  // workspace too small; would corrupt

    hipMemsetAsync(d_out, 0, sizeof(float), stream);
    hipMemsetAsync(xcat2, 0, (size_t)(64 * 2048 + 64 * 1024 + 64 * 1024) * 4, stream);

    prep_kernel<<<33, 256, 0, stream>>>(b1ih, b1hh, b2ih, b2hh, capmask, bsum1, bsum2, msum);
    conv_bf16<<<32000, 256, 0, stream>>>(embW, Wv16, 1024 * 32000);
    transp_conv<<<dim3(2048 / 32, 4096 / 32), 256, 0, stream>>>(W1ih, W1cat, 2048);
    transp_conv<<<dim3(1024 / 32, 4096 / 32), 256, 0, stream>>>(W1hh, W1cat + (size_t)2048 * 4096, 1024);
    transp_conv<<<dim3(1024 / 32, 4096 / 32), 256, 0, stream>>>(W2ih, W2cat, 1024);
    transp_conv<<<dim3(1024 / 32, 4096 / 32), 256, 0, stream>>>(W2hh, W2cat + (size_t)1024 * 4096, 1024);

    mean_kernel<<<512, 256, 0, stream>>>(action_feat, fm);
    // P1: video_feat = action_feat @ enc_img_W + b   [2560,1024]
    gemm_tiled<false, false><<<dim3(16, 40), 256, 0, stream>>>(
        action_feat, enc_img_W, vf, enc_img_b, 2560, 1024, 2048, 0);
    // P3: feat_h = fm @ enc_mean_W + b (split-K 4)
    gemm_tiled<false, true><<<dim3(16, 4), 256, 0, stream>>>(
        fm, enc_mean_W, p3part, nullptr, 64, 1024, 2048, 512);
    combine_p3<<<256, 256, 0, stream>>>(p3part, enc_mean_b, feat_h, xcat1);
    // P4: image_part = vf @ att_Ua + ba  [2560,1024] ([b][t][h] layout)
    gemm_tiled<false, false><<<dim3(16, 40), 256, 0, stream>>>(
        vf, att_Ua, imgp, att_ba, 2560, 1024, 1024, 0);

    for (int s = 0; s < kNS; ++s) {
        const float* hprev = (s == 0) ? feat_h : h2buf;
        gemm_tiled<false, true><<<dim3(16, 4), 256, 0, stream>>>(
            hprev, att_Wa, hWaP, nullptr, 64, 1024, 1024, 256);
        attn_kernel<<<64, 256, 0, stream>>>(
            hWaP, imgp, vf, att_w, video_mask, Wemb, captions, s, xcat1);
        gemm_tiled<true, true><<<dim3(64, 8), 256, 0, stream>>>(
            xcat1, W1cat, g1p, nullptr, 64, 4096, 3072, 384);
        cell_kernel<<<256, 256, 0, stream>>>(
            g1p, bsum1, c1, xcat1, 3072, 2048, xcat2, 2048, 0, nullptr);
        gemm_tiled<true, true><<<dim3(64, 8), 256, 0, stream>>>(
            xcat2, W2cat, g2p, nullptr, 64, 4096, 2048, 256);
        cell_kernel<<<256, 256, 0, stream>>>(
            g2p, bsum2, c2, xcat2, 2048, 1024, h2buf, 1024, 0, h2T);
        logits_kernel<<<dim3(63, 4, 2), 256, 0, stream>>>(h2T, Wv16, logitp);
        loss_kernel<<<64, 256, 0, stream>>>(
            logitp, embb, captions, msum, s, (float*)d_out);
    }
}

// Round 2
// 6091.091 us; speedup vs baseline: 1.2840x; 1.2840x over previous
//
#include <hip/hip_runtime.h>
#include <stdint.h>

constexpr int kB   = 64;
constexpr int kTV  = 40;
constexpr int kF   = 2048;
constexpr int kH   = 1024;
constexpr int kV   = 32000;
constexpr int kNS  = 30;
constexpr int kCAP = 31;

typedef __attribute__((ext_vector_type(8))) short bf16x8;
typedef __attribute__((ext_vector_type(4))) float f32x4;

__device__ __forceinline__ float sigm(float x) { return 1.f / (1.f + __expf(-x)); }
__device__ __forceinline__ float tanh_fast(float x) {
    float e = __expf(2.f * x);
    return 1.f - 2.f / (e + 1.f);
}
__device__ __forceinline__ unsigned short f2bf(float x) {
    unsigned u = __float_as_uint(x);
    return (unsigned short)((u + 0x7fffu + ((u >> 16) & 1u)) >> 16);
}
__device__ __forceinline__ float bf2f(unsigned short u) {
    return __uint_as_float((unsigned)u << 16);
}

// async global->LDS, 16B per lane. lds base wave-uniform; HW adds lane*16.
__device__ __forceinline__ void gl16(const unsigned short* g, unsigned short* lds) {
    __builtin_amdgcn_global_load_lds(
        (const __attribute__((address_space(1))) unsigned int*)(g),
        (__attribute__((address_space(3))) unsigned int*)(lds), 16, 0, 0);
}

// A-packed layout: [kt][ms][lane][j] ; value (row, col): ms=row>>4,
// lane=(row&15)+16*((kc>>2)&3), j=(kc&3)+4*(kc>>4), kc=col&31, kt=col>>5.
__device__ __forceinline__ void store_packedA(unsigned short* base, int row, int col,
                                              unsigned short v) {
    int kt = col >> 5, kc = col & 31, ms = row >> 4;
    int l = (row & 15) + (((kc >> 2) & 3) << 4);
    int j = (kc & 3) + ((kc >> 4) << 2);
    base[((((size_t)kt * 4 + ms) * 64 + l) << 3) + j] = v;
}

// ---------------- MFMA K-loop (double-buffered, 2-phase) ----------------
// Block = 256 thr (4 waves). Output: 64 rows x (64*NSPW) cols.
// Ap: [KT][4][64][8] bf16 (this M-panel). Bp: [KT][4*NSPW][64][8] (this N-panel).
template <int NSPW>
__device__ __forceinline__ void mfma_kloop(
    const unsigned short* __restrict__ Ap, const unsigned short* __restrict__ Bp,
    int KT, unsigned short* Asm, unsigned short* Bsm, int w, int l,
    f32x4 acc[4][NSPW])
{
    const int BSTEP = 2048 * NSPW;
    gl16(Ap + w * 512 + l * 8, Asm + w * 512);
#pragma unroll
    for (int i = 0; i < NSPW; ++i)
        gl16(Bp + (w * NSPW + i) * 512 + l * 8, Bsm + (w * NSPW + i) * 512);
    __syncthreads();
    for (int kt = 0; kt < KT; ++kt) {
        int cur = kt & 1;
        if (kt + 1 < KT) {
            gl16(Ap + (size_t)(kt + 1) * 2048 + w * 512 + l * 8,
                 Asm + (cur ^ 1) * 2048 + w * 512);
#pragma unroll
            for (int i = 0; i < NSPW; ++i)
                gl16(Bp + (size_t)(kt + 1) * BSTEP + (w * NSPW + i) * 512 + l * 8,
                     Bsm + (cur ^ 1) * BSTEP + (w * NSPW + i) * 512);
        }
        bf16x8 bfr[NSPW];
#pragma unroll
        for (int i = 0; i < NSPW; ++i)
            bfr[i] = *(const bf16x8*)(Bsm + cur * BSTEP + ((w * NSPW + i) * 64 + l) * 8);
#pragma unroll
        for (int ms = 0; ms < 4; ++ms) {
            bf16x8 afr = *(const bf16x8*)(Asm + cur * 2048 + (ms * 64 + l) * 8);
#pragma unroll
            for (int i = 0; i < NSPW; ++i)
                acc[ms][i] = __builtin_amdgcn_mfma_f32_16x16x32_bf16(afr, bfr[i],
                                                                     acc[ms][i], 0, 0, 0);
        }
        __syncthreads();
    }
}

// ---------------- packing kernels ----------------
// [K][N] fp32 row-major -> B-fragment-packed bf16 ([nb][kt][S ns][64][8])
__global__ __launch_bounds__(256) void pack_kn(const float* __restrict__ W,
                                               unsigned short* __restrict__ out,
                                               int K, int N, int S)
{
    size_t tid = (size_t)blockIdx.x * 256 + threadIdx.x;
    int l = tid & 63;
    size_t f = tid >> 6;
    int ns = f % S; f /= S;
    int KT = K >> 5;
    int kt = f % KT; int nb = f / KT;
    int n = nb * (16 * S) + ns * 16 + (l & 15);
    int kb = kt * 32 + ((l >> 4) & 3) * 4;
    __align__(16) unsigned short o[8];
#pragma unroll
    for (int j = 0; j < 8; ++j) {
        int k = kb + (j & 3) + ((j >> 2) << 4);
        o[j] = f2bf(W[(size_t)k * N + n]);
    }
    *(uint4*)(out + tid * 8) = *(const uint4*)o;
}

// LSTM weights: Wih[4096][Kih], Whh[4096][1024] -> packed [nb][kt][4][64][8]
// with gate-interleaved cols: packed col = nb*64 + gate*16 + ulocal.
__global__ __launch_bounds__(256) void pack_lstm(const float* __restrict__ Wih,
                                                 const float* __restrict__ Whh,
                                                 int Kih, int KT,
                                                 unsigned short* __restrict__ out)
{
    size_t tid = (size_t)blockIdx.x * 256 + threadIdx.x;
    int l = tid & 63;
    size_t f = tid >> 6;
    int g = f & 3; f >>= 2;
    int kt = f % KT; int nb = f / KT;
    int n_orig = g * 1024 + nb * 16 + (l & 15);
    int kb = kt * 32 + ((l >> 4) & 3) * 4;
    __align__(16) unsigned short o[8];
#pragma unroll
    for (int j = 0; j < 8; ++j) {
        int k = kb + (j & 3) + ((j >> 2) << 4);
        float v = (k < Kih) ? Wih[(size_t)n_orig * Kih + k]
                            : Whh[(size_t)n_orig * 1024 + (k - Kih)];
        o[j] = f2bf(v);
    }
    *(uint4*)(out + tid * 8) = *(const uint4*)o;
}

// action_feat [2560][2048] fp32 -> A-packed bf16 [mb(40)][kt(64)][ms][64][8]
__global__ __launch_bounds__(256) void pack_af(const float* __restrict__ af,
                                               unsigned short* __restrict__ out)
{
    size_t tid = (size_t)blockIdx.x * 256 + threadIdx.x;
    int l = tid & 63;
    size_t f = tid >> 6;
    int ms = f & 3; f >>= 2;
    int kt = f & 63; int mb = f >> 6;
    int row = mb * 64 + ms * 16 + (l & 15);
    int kb = kt * 32 + ((l >> 4) & 3) * 4;
    __align__(16) unsigned short o[8];
#pragma unroll
    for (int j = 0; j < 8; ++j) {
        int k = kb + (j & 3) + ((j >> 2) << 4);
        o[j] = f2bf(af[(size_t)row * kF + k]);
    }
    *(uint4*)(out + tid * 8) = *(const uint4*)o;
}

// feat_mean A-packed bf16 [kt(64)][ms][64][8]
__global__ __launch_bounds__(256) void mean_pack(const float* __restrict__ af,
                                                 unsigned short* __restrict__ out)
{
    int tid = blockIdx.x * 256 + threadIdx.x;   // 16384
    int l = tid & 63;
    int f = tid >> 6;
    int ms = f & 3; int kt = f >> 2;
    int b = ms * 16 + (l & 15);
    int kb = kt * 32 + ((l >> 4) & 3) * 4;
    __align__(16) unsigned short o[8];
#pragma unroll
    for (int j = 0; j < 8; ++j) {
        int k = kb + (j & 3) + ((j >> 2) << 4);
        float s = 0.f;
        for (int t = 0; t < kTV; ++t) s += af[((size_t)b * kTV + t) * kF + k];
        o[j] = f2bf(s * (1.f / kTV));
    }
    *(uint4*)(out + (size_t)tid * 8) = *(const uint4*)o;
}

// ---------------- bias/mask prep ----------------
__global__ __launch_bounds__(256) void prep_kernel(
    const float* __restrict__ bih1, const float* __restrict__ bhh1,
    const float* __restrict__ bih2, const float* __restrict__ bhh2,
    const float* __restrict__ capmask,
    float* __restrict__ bsum1, float* __restrict__ bsum2, float* __restrict__ msum)
{
    int g = blockIdx.x * 256 + threadIdx.x;
    if (g < 4096) bsum1[g] = bih1[g] + bhh1[g];
    else if (g < 8192) { int j = g - 4096; bsum2[j] = bih2[j] + bhh2[j]; }
    else if (g < 8192 + kNS) {
        int t = g - 8192;
        float s = 0.f;
        for (int b = 0; b < kB; ++b) s += capmask[b * kCAP + t + 1];
        msum[t] = s;
    }
}

// ---------------- encoder GEMMs (P1/P4): out = A@B + bias ----------------
__global__ __launch_bounds__(256) void enc_gemm(
    const unsigned short* __restrict__ Ap, const unsigned short* __restrict__ Bp,
    const float* __restrict__ bias, float* __restrict__ outF,
    unsigned short* __restrict__ outP, int KT)
{
    __shared__ unsigned short Asm[2][2048];
    __shared__ unsigned short Bsm[2][2048];
    int tid = threadIdx.x, w = tid >> 6, l = tid & 63;
    int nb = blockIdx.x, mb = blockIdx.y;
    f32x4 acc[4][1] = {};
    mfma_kloop<1>(Ap + (size_t)mb * KT * 2048, Bp + (size_t)nb * KT * 2048, KT,
                  &Asm[0][0], &Bsm[0][0], w, l, acc);
    int ul = l & 15, sg = l >> 4;
    int n = nb * 64 + w * 16 + ul;
    float bv = bias[n];
#pragma unroll
    for (int ms = 0; ms < 4; ++ms)
#pragma unroll
        for (int r = 0; r < 4; ++r) {
            int rl = ms * 16 + sg * 4 + r;
            int row = mb * 64 + rl;
            float v = acc[ms][0][r] + bv;
            outF[(size_t)row * kH + n] = v;
            if (outP) store_packedA(outP + (size_t)mb * 65536, rl, n, f2bf(v));
        }
}

// ---------------- P3: feat_h -> xcat1p(+2048) and h2p(+0), bf16 ----------------
__global__ __launch_bounds__(256) void p3_gemm(
    const unsigned short* __restrict__ Ap, const unsigned short* __restrict__ Bp,
    const float* __restrict__ bias, unsigned short* __restrict__ xcat1p,
    unsigned short* __restrict__ h2p)
{
    __shared__ unsigned short Asm[2][2048];
    __shared__ unsigned short Bsm[2][2048];
    int tid = threadIdx.x, w = tid >> 6, l = tid & 63;
    int nb = blockIdx.x;
    f32x4 acc[4][1] = {};
    mfma_kloop<1>(Ap, Bp + (size_t)nb * 64 * 2048, 64, &Asm[0][0], &Bsm[0][0], w, l, acc);
    int ul = l & 15, sg = l >> 4;
    int n = nb * 64 + w * 16 + ul;
    float bv = bias[n];
#pragma unroll
    for (int ms = 0; ms < 4; ++ms)
#pragma unroll
        for (int r = 0; r < 4; ++r) {
            int row = ms * 16 + sg * 4 + r;
            unsigned short hb = f2bf(acc[ms][0][r] + bv);
            store_packedA(xcat1p, row, 2048 + n, hb);
            store_packedA(h2p, row, n, hb);
        }
}

// ---------------- hWa = h_prev @ att_Wa  [64][1024] fp32 ----------------
__global__ __launch_bounds__(256) void hwa_gemm(
    const unsigned short* __restrict__ h2p, const unsigned short* __restrict__ WaP,
    float* __restrict__ hw)
{
    __shared__ unsigned short Asm[2][2048];
    __shared__ unsigned short Bsm[2][2048];
    int tid = threadIdx.x, w = tid >> 6, l = tid & 63;
    int nb = blockIdx.x;
    f32x4 acc[4][1] = {};
    mfma_kloop<1>(h2p, WaP + (size_t)nb * 32 * 2048, 32, &Asm[0][0], &Bsm[0][0], w, l, acc);
    int ul = l & 15, sg = l >> 4;
    int n = nb * 64 + w * 16 + ul;
#pragma unroll
    for (int ms = 0; ms < 4; ++ms)
#pragma unroll
        for (int r = 0; r < 4; ++r)
            hw[(size_t)(ms * 16 + sg * 4 + r) * kH + n] = acc[ms][0][r];
}

// ---------------- fused attention (per batch row) ----------------
__global__ __launch_bounds__(256) void attn_fused(
    const float* __restrict__ hw, const float* __restrict__ imgp,
    const float* __restrict__ attw, const float* __restrict__ vf,
    const float* __restrict__ vmask, const float* __restrict__ Wemb,
    const int* __restrict__ captions, int s, unsigned short* __restrict__ xcat1p)
{
    __shared__ float hwv[kH];
    __shared__ float es[48];
    int b = blockIdx.x, tid = threadIdx.x;
    for (int i = tid; i < kH; i += 256) hwv[i] = hw[(size_t)b * kH + i];
    __syncthreads();
    int w = tid >> 6, l = tid & 63;
    for (int t = w; t < kTV; t += 4) {
        const float* ip = imgp + ((size_t)b * kTV + t) * kH;
        float p = 0.f;
#pragma unroll
        for (int hh = 0; hh < 16; ++hh) {
            int h = hh * 64 + l;
            p += tanh_fast(hwv[h] + ip[h]) * attw[h];
        }
        for (int off = 32; off; off >>= 1) p += __shfl_down(p, off);
        if (l == 0) es[t] = p;
    }
    __syncthreads();
    float mx = -1e30f;
    for (int t = 0; t < kTV; ++t) mx = fmaxf(mx, es[t]);
    const float* vm = vmask + b * kTV;
    float den = 0.f;
    for (int t = 0; t < kTV; ++t) den += vm[t] * __expf(es[t] - mx);
    den = den + (den == 0.f ? 1.f : 0.f) + 1e-9f;
    int h0 = tid * 4;
    float4 av = {0.f, 0.f, 0.f, 0.f};
    for (int t = 0; t < kTV; ++t) {
        float wgt = vm[t] * __expf(es[t] - mx) / den;
        float4 v = *(const float4*)(vf + ((size_t)b * kTV + t) * kH + h0);
        av.x += wgt * v.x; av.y += wgt * v.y; av.z += wgt * v.z; av.w += wgt * v.w;
    }
    store_packedA(xcat1p, b, 1024 + h0 + 0, f2bf(av.x));
    store_packedA(xcat1p, b, 1024 + h0 + 1, f2bf(av.y));
    store_packedA(xcat1p, b, 1024 + h0 + 2, f2bf(av.z));
    store_packedA(xcat1p, b, 1024 + h0 + 3, f2bf(av.w));
    int word = captions[b * kCAP + s];
    float4 e4 = *(const float4*)(Wemb + (size_t)word * kH + h0);
    store_packedA(xcat1p, b, h0 + 0, f2bf(e4.x));
    store_packedA(xcat1p, b, h0 + 1, f2bf(e4.y));
    store_packedA(xcat1p, b, h0 + 2, f2bf(e4.z));
    store_packedA(xcat1p, b, h0 + 3, f2bf(e4.w));
}

// ---------------- gates GEMM + fused LSTM cell ----------------
// Weight cols gate-interleaved: block nb covers units nb*16..+15, waves = gates.
__global__ __launch_bounds__(256) void gates_cell(
    const unsigned short* __restrict__ Ap, const unsigned short* __restrict__ Bp,
    int KT, const float* __restrict__ bsum, float* __restrict__ cbuf,
    unsigned short* __restrict__ dA, int ofsA,
    unsigned short* __restrict__ dB, int ofsB)
{
    __shared__ unsigned short Asm[2][2048];
    __shared__ unsigned short Bsm[2][2048];
    __shared__ float gsm[4][64][17];
    int tid = threadIdx.x, w = tid >> 6, l = tid & 63, nb = blockIdx.x;
    f32x4 acc[4][1] = {};
    mfma_kloop<1>(Ap, Bp + (size_t)nb * KT * 2048, KT, &Asm[0][0], &Bsm[0][0], w, l, acc);
    int ul = l & 15, sg = l >> 4;
    float bv = bsum[w * 1024 + nb * 16 + ul];
#pragma unroll
    for (int ms = 0; ms < 4; ++ms)
#pragma unroll
        for (int r = 0; r < 4; ++r)
            gsm[w][ms * 16 + sg * 4 + r][ul] = acc[ms][0][r] + bv;
    __syncthreads();
#pragma unroll
    for (int q = 0; q < 4; ++q) {
        int idx = tid * 4 + q;
        int row = idx >> 4, uc = idx & 15, u = nb * 16 + uc;
        float gi = gsm[0][row][uc], gf = gsm[1][row][uc];
        float gg = gsm[2][row][uc], go = gsm[3][row][uc];
        float c = sigm(gf) * cbuf[(size_t)row * kH + u] + sigm(gi) * tanh_fast(gg);
        cbuf[(size_t)row * kH + u] = c;
        unsigned short hb = f2bf(sigm(go) * tanh_fast(c));
        store_packedA(dA, row, ofsA + u, hb);
        store_packedA(dB, row, ofsB + u, hb);
    }
}

// ---------------- logits GEMM + fused partial log-softmax ----------------
__global__ __launch_bounds__(256) void logits_k(
    const unsigned short* __restrict__ h2p, const unsigned short* __restrict__ WvP,
    const float* __restrict__ embb, const int* __restrict__ captions, int s,
    float* __restrict__ pmax, float* __restrict__ psum, float* __restrict__ tlog)
{
    __shared__ unsigned short Asm[2][2048];
    __shared__ unsigned short Bsm[2][4096];
    __shared__ float rmax[4][64];
    __shared__ float rsum[4][64];
    __shared__ int stgt[64];
    int tid = threadIdx.x, w = tid >> 6, l = tid & 63, nb = blockIdx.x;
    if (tid < 64) stgt[tid] = captions[tid * kCAP + s + 1];
    f32x4 acc[4][2] = {};
    mfma_kloop<2>(h2p, WvP + (size_t)nb * 32 * 4096, 32, &Asm[0][0], &Bsm[0][0], w, l, acc);
    int ul = l & 15, sg = l >> 4;
    int n0 = nb * 128 + (2 * w + 0) * 16 + ul;
    int n1 = nb * 128 + (2 * w + 1) * 16 + ul;
    float b0 = embb[n0], b1 = embb[n1];
    float lm[4][4];
#pragma unroll
    for (int ms = 0; ms < 4; ++ms)
#pragma unroll
        for (int r = 0; r < 4; ++r)
            lm[ms][r] = fmaxf(acc[ms][0][r] + b0, acc[ms][1][r] + b1);
#pragma unroll
    for (int m = 1; m < 16; m <<= 1)
#pragma unroll
        for (int ms = 0; ms < 4; ++ms)
#pragma unroll
            for (int r = 0; r < 4; ++r)
                lm[ms][r] = fmaxf(lm[ms][r], __shfl_xor(lm[ms][r], m));
    if (ul == 0)
#pragma unroll
        for (int ms = 0; ms < 4; ++ms)
#pragma unroll
            for (int r = 0; r < 4; ++r)
                rmax[w][ms * 16 + sg * 4 + r] = lm[ms][r];
    __syncthreads();
    float ls[4][4];
#pragma unroll
    for (int ms = 0; ms < 4; ++ms)
#pragma unroll
        for (int r = 0; r < 4; ++r) {
            int row = ms * 16 + sg * 4 + r;
            float m4 = fmaxf(fmaxf(rmax[0][row], rmax[1][row]),
                             fmaxf(rmax[2][row], rmax[3][row]));
            float v0 = acc[ms][0][r] + b0, v1 = acc[ms][1][r] + b1;
            ls[ms][r] = __expf(v0 - m4) + __expf(v1 - m4);
            if (n0 == stgt[row]) tlog[row] = v0;
            if (n1 == stgt[row]) tlog[row] = v1;
        }
#pragma unroll
    for (int m = 1; m < 16; m <<= 1)
#pragma unroll
        for (int ms = 0; ms < 4; ++ms)
#pragma unroll
            for (int r = 0; r < 4; ++r)
                ls[ms][r] += __shfl_xor(ls[ms][r], m);
    if (ul == 0)
#pragma unroll
        for (int ms = 0; ms < 4; ++ms)
#pragma unroll
            for (int r = 0; r < 4; ++r)
                rsum[w][ms * 16 + sg * 4 + r] = ls[ms][r];
    __syncthreads();
    if (tid < 64) {
        float m4 = fmaxf(fmaxf(rmax[0][tid], rmax[1][tid]),
                         fmaxf(rmax[2][tid], rmax[3][tid]));
        float t4 = rsum[0][tid] + rsum[1][tid] + rsum[2][tid] + rsum[3][tid];
        pmax[(size_t)nb * 64 + tid] = m4;
        psum[(size_t)nb * 64 + tid] = t4;
    }
}

// ---------------- final loss reduce over 250 vocab-blocks ----------------
__global__ void loss_k(const float* __restrict__ pmax, const float* __restrict__ psum,
                       const float* __restrict__ tlog, const float* __restrict__ msum,
                       int s, float* __restrict__ out)
{
    int b = threadIdx.x;  // 64
    float mx = -1e30f;
    for (int i = 0; i < 250; ++i) mx = fmaxf(mx, pmax[i * 64 + b]);
    float tot = 0.f;
    for (int i = 0; i < 250; ++i) tot += psum[i * 64 + b] * __expf(pmax[i * 64 + b] - mx);
    float logp = tlog[b] - mx - __logf(tot);
    float v = -logp * msum[s] * (1.f / (64.f * 64.f));
    for (int off = 32; off; off >>= 1) v += __shfl_down(v, off);
    if (b == 0) atomicAdd(out, v);
}

// ---------------- host ----------------
extern "C" void kernel_launch(void* const* d_in, const int* in_sizes, int n_in,
                              void* d_out, int out_size, void* d_ws, size_t ws_size,
                              hipStream_t stream)
{
    const float* action_feat = (const float*)d_in[1];
    const float* video_mask  = (const float*)d_in[3];
    const int*   captions    = (const int*)d_in[4];
    const float* capmask     = (const float*)d_in[5];
    const float* enc_img_W   = (const float*)d_in[6];
    const float* enc_img_b   = (const float*)d_in[7];
    const float* enc_mean_W  = (const float*)d_in[8];
    const float* enc_mean_b  = (const float*)d_in[9];
    const float* att_w       = (const float*)d_in[10];
    const float* att_Wa      = (const float*)d_in[11];
    const float* att_Ua      = (const float*)d_in[12];
    const float* att_ba      = (const float*)d_in[13];
    const float* Wemb        = (const float*)d_in[14];
    const float* embW        = (const float*)d_in[15];
    const float* embb        = (const float*)d_in[16];
    const float* W1ih        = (const float*)d_in[17];
    const float* W1hh        = (const float*)d_in[18];
    const float* b1ih        = (const float*)d_in[19];
    const float* b1hh        = (const float*)d_in[20];
    const float* W2ih        = (const float*)d_in[21];
    const float* W2hh        = (const float*)d_in[22];
    const float* b2ih        = (const float*)d_in[23];
    const float* b2hh        = (const float*)d_in[24];

    char* base = (char*)d_ws;
    size_t off = 0;
    auto alloc = [&](size_t bytes) {
        char* p = base + off;
        off = (off + bytes + 255) & ~(size_t)255;
        return p;
    };

    float* vf    = (float*)alloc((size_t)2560 * 1024 * 4);
    float* imgp  = (float*)alloc((size_t)2560 * 1024 * 4);
    float* hw    = (float*)alloc((size_t)64 * 1024 * 4);
    float* bsum1 = (float*)alloc(4096 * 4);
    float* bsum2 = (float*)alloc(4096 * 4);
    float* msum  = (float*)alloc(32 * 4);
    float* pmax  = (float*)alloc((size_t)250 * 64 * 4);
    float* psum  = (float*)alloc((size_t)250 * 64 * 4);
    float* tlog  = (float*)alloc(64 * 4);
    // zero-init block: xcat2p[2], c1, c2 (contiguous)
    unsigned short* x2p0 = (unsigned short*)alloc((size_t)64 * 2048 * 2);
    unsigned short* x2p1 = (unsigned short*)alloc((size_t)64 * 2048 * 2);
    float* c1    = (float*)alloc((size_t)64 * 1024 * 4);
    float* c2    = (float*)alloc((size_t)64 * 1024 * 4);
    size_t zlen  = (size_t)(c2 + 64 * 1024 - (float*)x2p0) * 4;

    unsigned short* x1p0 = (unsigned short*)alloc((size_t)64 * 3072 * 2);
    unsigned short* x1p1 = (unsigned short*)alloc((size_t)64 * 3072 * 2);
    unsigned short* h2p  = (unsigned short*)alloc((size_t)64 * 1024 * 2);
    unsigned short* afP  = (unsigned short*)alloc((size_t)2560 * 2048 * 2);
    unsigned short* vfP  = (unsigned short*)alloc((size_t)2560 * 1024 * 2);
    unsigned short* fmP  = (unsigned short*)alloc((size_t)64 * 2048 * 2);
    unsigned short* WiP  = (unsigned short*)alloc((size_t)2048 * 1024 * 2);
    unsigned short* WmP  = (unsigned short*)alloc((size_t)2048 * 1024 * 2);
    unsigned short* WuaP = (unsigned short*)alloc((size_t)1024 * 1024 * 2);
    unsigned short* WaP  = (unsigned short*)alloc((size_t)1024 * 1024 * 2);
    unsigned short* W1p  = (unsigned short*)alloc((size_t)3072 * 4096 * 2);
    unsigned short* W2p  = (unsigned short*)alloc((size_t)2048 * 4096 * 2);
    unsigned short* WvP  = (unsigned short*)alloc((size_t)1024 * 32000 * 2);
    if (off > ws_size) return;

    hipMemsetAsync(d_out, 0, 4, stream);
    hipMemsetAsync(x2p0, 0, zlen, stream);

    prep_kernel<<<33, 256, 0, stream>>>(b1ih, b1hh, b2ih, b2hh, capmask,
                                        bsum1, bsum2, msum);
    pack_af<<<2560, 256, 0, stream>>>(action_feat, afP);
    mean_pack<<<64, 256, 0, stream>>>(action_feat, fmP);
    pack_kn<<<1024, 256, 0, stream>>>(enc_img_W, WiP, 2048, 1024, 4);
    pack_kn<<<1024, 256, 0, stream>>>(enc_mean_W, WmP, 2048, 1024, 4);
    pack_kn<<<512, 256, 0, stream>>>(att_Ua, WuaP, 1024, 1024, 4);
    pack_kn<<<512, 256, 0, stream>>>(att_Wa, WaP, 1024, 1024, 4);
    pack_kn<<<16000, 256, 0, stream>>>(embW, WvP, 1024, 32000, 8);
    pack_lstm<<<6144, 256, 0, stream>>>(W1ih, W1hh, 2048, 96, W1p);
    pack_lstm<<<4096, 256, 0, stream>>>(W2ih, W2hh, 1024, 64, W2p);

    // P1: vf = action_feat @ enc_img_W + b ; also packed bf16 copy for P4
    enc_gemm<<<dim3(16, 40), 256, 0, stream>>>(afP, WiP, enc_img_b, vf, vfP, 64);
    // P3: feat_h -> xcat1p[0] h1-slot and h2p (initial h_prev)
    p3_gemm<<<16, 256, 0, stream>>>(fmP, WmP, enc_mean_b, x1p0, h2p);
    // P4: imgp = vf @ att_Ua + ba
    enc_gemm<<<dim3(16, 40), 256, 0, stream>>>(vfP, WuaP, att_ba, imgp, nullptr, 32);

    for (int s = 0; s < kNS; ++s) {
        unsigned short* x1c = (s & 1) ? x1p1 : x1p0;
        unsigned short* x1n = (s & 1) ? x1p0 : x1p1;
        unsigned short* x2c = (s & 1) ? x2p1 : x2p0;
        unsigned short* x2n = (s & 1) ? x2p0 : x2p1;
        hwa_gemm<<<16, 256, 0, stream>>>(h2p, WaP, hw);
        attn_fused<<<64, 256, 0, stream>>>(hw, imgp, att_w, vf, video_mask,
                                           Wemb, captions, s, x1c);
        gates_cell<<<64, 256, 0, stream>>>(x1c, W1p, 96, bsum1, c1,
                                           x1n, 2048, x2c, 0);
        gates_cell<<<64, 256, 0, stream>>>(x2c, W2p, 64, bsum2, c2,
                                           x2n, 1024, h2p, 0);
        logits_k<<<250, 256, 0, stream>>>(h2p, WvP, embb, captions, s,
                                          pmax, psum, tlog);
        loss_k<<<1, 64, 0, stream>>>(pmax, psum, tlog, msum, s, (float*)d_out);
    }
}

// Round 3
// 4329.230 us; speedup vs baseline: 1.8065x; 1.4070x over previous
//
#include <hip/hip_runtime.h>
#include <stdint.h>

constexpr int kB   = 64;
constexpr int kTV  = 40;
constexpr int kF   = 2048;
constexpr int kH   = 1024;
constexpr int kV   = 32000;
constexpr int kNS  = 30;
constexpr int kCAP = 31;

typedef __attribute__((ext_vector_type(8))) short bf16x8;
typedef __attribute__((ext_vector_type(4))) float f32x4;

__device__ __forceinline__ float sigm(float x) { return 1.f / (1.f + __expf(-x)); }
__device__ __forceinline__ float tanh_fast(float x) {
    float e = __expf(2.f * x);
    return 1.f - 2.f / (e + 1.f);
}
__device__ __forceinline__ unsigned short f2bf(float x) {
    unsigned u = __float_as_uint(x);
    return (unsigned short)((u + 0x7fffu + ((u >> 16) & 1u)) >> 16);
}

__device__ __forceinline__ void gl16(const unsigned short* g, unsigned short* lds) {
    __builtin_amdgcn_global_load_lds(
        (const __attribute__((address_space(1))) unsigned int*)(g),
        (__attribute__((address_space(3))) unsigned int*)(lds), 16, 0, 0);
}

template <int N>
__device__ __forceinline__ void waitv() {
    asm volatile("s_waitcnt vmcnt(%0)" :: "n"(N) : "memory");
}
__device__ __forceinline__ void barrier_raw() {
    __builtin_amdgcn_s_barrier();
    asm volatile("" ::: "memory");   // pin LDS reads below the barrier
}

// A-packed layout: [kt][ms][lane][j]; (row,col): ms=row>>4,
// lane=(row&15)+16*((kc>>2)&3), j=(kc&3)+4*(kc>>4), kc=col&31, kt=col>>5.
__device__ __forceinline__ void store_packedA(unsigned short* base, int row, int col,
                                              unsigned short v) {
    int kt = col >> 5, kc = col & 31, ms = row >> 4;
    int l = (row & 15) + (((kc >> 2) & 3) << 4);
    int j = (kc & 3) + ((kc >> 4) << 2);
    base[((((size_t)kt * 4 + ms) * 64 + l) << 3) + j] = v;
}

// ---------------- 3-deep pipelined MFMA K-loop ----------------
// Block = 256 thr (4 waves). Out: 64 rows x (64*NSPW) cols.
// Ap: [KT][4][64][8] bf16. Bp: [KT][4*NSPW][64][8] bf16.
template <int NSPW, int KT>
__device__ __forceinline__ void mfma_kloop(
    const unsigned short* __restrict__ Ap, const unsigned short* __restrict__ Bp,
    unsigned short* Asm, unsigned short* Bsm, int w, int l, f32x4 acc[4][NSPW])
{
    constexpr int BSTEP = 2048 * NSPW;
    constexpr int LPT = 1 + NSPW;   // vmem ops per stage per wave
    auto stage = [&](int t, int slot) {
        gl16(Ap + (size_t)t * 2048 + w * 512 + l * 8, Asm + slot * 2048 + w * 512);
#pragma unroll
        for (int i = 0; i < NSPW; ++i)
            gl16(Bp + (size_t)t * BSTEP + (w * NSPW + i) * 512 + l * 8,
                 Bsm + slot * BSTEP + (w * NSPW + i) * 512);
    };
    stage(0, 0); stage(1, 1); stage(2, 2);
#pragma unroll 1
    for (int t = 0; t < KT; ++t) {
        int slot = t % 3;
        int rem = KT - 1 - t;
        if (rem >= 2) waitv<2 * LPT>();
        else if (rem == 1) waitv<LPT>();
        else waitv<0>();
        barrier_raw();                       // tile t visible to all waves
        bf16x8 bfr[NSPW], afr[4];
#pragma unroll
        for (int i = 0; i < NSPW; ++i)
            bfr[i] = *(const bf16x8*)(Bsm + slot * BSTEP + ((w * NSPW + i) * 64 + l) * 8);
#pragma unroll
        for (int ms = 0; ms < 4; ++ms)
            afr[ms] = *(const bf16x8*)(Asm + slot * 2048 + (ms * 64 + l) * 8);
#pragma unroll
        for (int ms = 0; ms < 4; ++ms)
#pragma unroll
            for (int i = 0; i < NSPW; ++i)
                acc[ms][i] = __builtin_amdgcn_mfma_f32_16x16x32_bf16(
                    afr[ms], bfr[i], acc[ms][i], 0, 0, 0);
        __builtin_amdgcn_sched_barrier(0);
        barrier_raw();                       // all waves done reading slot
        if (t + 3 < KT) stage(t + 3, slot);
    }
}

// ---------------- packing: row-major source(s) -> fragment tiles ----------------
// Block covers 16 source rows (one group) x 128 k. grid(Ktot/128, ngroups).
__global__ __launch_bounds__(256) void pack_rm(
    const float* __restrict__ p0, int ld0, int ksplit,
    const float* __restrict__ p1, int ld1,
    int NGRP, int GS, int HS, int KT,
    unsigned short* __restrict__ out)
{
    __shared__ unsigned short tile[16][136];
    int kb = blockIdx.x * 128;
    int grp = blockIdx.y;
    int row0 = (grp % NGRP) * GS + (grp / NGRP) * HS;
    int tid = threadIdx.x;
    int r = tid >> 5, c4 = (tid & 31) * 4;
#pragma unroll
    for (int pass = 0; pass < 2; ++pass) {
        int rr = r + pass * 8;
        int row = row0 + rr;
        int k = kb + c4;
        float4 v;
        if (k < ksplit) v = *(const float4*)(p0 + (size_t)row * ld0 + k);
        else            v = *(const float4*)(p1 + (size_t)row * ld1 + (k - ksplit));
        ushort4 o; o.x = f2bf(v.x); o.y = f2bf(v.y); o.z = f2bf(v.z); o.w = f2bf(v.w);
        *(ushort4*)&tile[rr][c4] = o;
    }
    __syncthreads();
    int ktl = tid >> 6, l = tid & 63, ul = l & 15, q = (l >> 4) & 3;
    __align__(16) unsigned short o2[8];
#pragma unroll
    for (int j = 0; j < 8; ++j) {
        int kc = (j & 3) + q * 4 + ((j >> 2) << 4);
        o2[j] = tile[ul][ktl * 32 + kc];
    }
    int kt = (kb >> 5) + ktl;
    size_t base = (((size_t)(grp / NGRP) * KT + kt) * NGRP + (grp % NGRP)) * 512;
    *(uint4*)(out + base + (size_t)l * 8) = *(const uint4*)o2;
}

// ---------------- packing: [K][N] source (vocab) -> B tiles, S=8 ----------------
__global__ __launch_bounds__(256) void pack_cm(const float* __restrict__ W,
                                               unsigned short* __restrict__ out)
{
    __shared__ unsigned short tile[32][136];
    int n0 = blockIdx.x * 128, k0 = blockIdx.y * 32;
    int tid = threadIdx.x;
    int r = tid >> 5, c4 = (tid & 31) * 4;
#pragma unroll
    for (int pass = 0; pass < 4; ++pass) {
        int rr = r + pass * 8;
        float4 v = *(const float4*)(W + (size_t)(k0 + rr) * kV + n0 + c4);
        ushort4 o; o.x = f2bf(v.x); o.y = f2bf(v.y); o.z = f2bf(v.z); o.w = f2bf(v.w);
        *(ushort4*)&tile[rr][c4] = o;
    }
    __syncthreads();
    int ns = tid >> 5, lp = (tid & 31) * 2;
    size_t base = (((size_t)blockIdx.x * 32 + blockIdx.y) * 8 + ns) * 512;
    __align__(16) unsigned short o2[16];
#pragma unroll
    for (int li = 0; li < 2; ++li) {
        int l = lp + li, ul = l & 15, q = (l >> 4) & 3;
#pragma unroll
        for (int j = 0; j < 8; ++j) {
            int kc = (j & 3) + q * 4 + ((j >> 2) << 4);
            o2[li * 8 + j] = tile[kc][ns * 16 + ul];
        }
    }
    *(uint4*)(out + base + lp * 8) = *(const uint4*)&o2[0];
    *(uint4*)(out + base + lp * 8 + 8) = *(const uint4*)&o2[8];
}

// small weights: old gather-style pack ([K][N] -> [nb][kt][S][64][8])
__global__ __launch_bounds__(256) void pack_kn(const float* __restrict__ W,
                                               unsigned short* __restrict__ out,
                                               int K, int N, int S)
{
    size_t tid = (size_t)blockIdx.x * 256 + threadIdx.x;
    int l = tid & 63;
    size_t f = tid >> 6;
    int ns = f % S; f /= S;
    int KT = K >> 5;
    int kt = f % KT; int nb = f / KT;
    int n = nb * (16 * S) + ns * 16 + (l & 15);
    int kb = kt * 32 + ((l >> 4) & 3) * 4;
    __align__(16) unsigned short o[8];
#pragma unroll
    for (int j = 0; j < 8; ++j) {
        int k = kb + (j & 3) + ((j >> 2) << 4);
        o[j] = f2bf(W[(size_t)k * N + n]);
    }
    *(uint4*)(out + tid * 8) = *(const uint4*)o;
}

// ---------------- feat mean (coalesced) ----------------
__global__ __launch_bounds__(256) void mean_f(const float* __restrict__ af,
                                              float* __restrict__ fm)
{
    int b = blockIdx.x, tid = threadIdx.x;
    const float* base = af + (size_t)b * kTV * kF;
    float a[8] = {};
    for (int t = 0; t < kTV; ++t) {
        const float* rp = base + (size_t)t * kF + tid * 8;
        float4 v0 = *(const float4*)rp;
        float4 v1 = *(const float4*)(rp + 4);
        a[0] += v0.x; a[1] += v0.y; a[2] += v0.z; a[3] += v0.w;
        a[4] += v1.x; a[5] += v1.y; a[6] += v1.z; a[7] += v1.w;
    }
    float* op = fm + (size_t)b * kF + tid * 8;
#pragma unroll
    for (int j = 0; j < 8; ++j) op[j] = a[j] * (1.f / kTV);
}

// ---------------- bias/mask prep ----------------
__global__ __launch_bounds__(256) void prep_kernel(
    const float* __restrict__ bih1, const float* __restrict__ bhh1,
    const float* __restrict__ bih2, const float* __restrict__ bhh2,
    const float* __restrict__ capmask,
    float* __restrict__ bsum1, float* __restrict__ bsum2, float* __restrict__ msum)
{
    int g = blockIdx.x * 256 + threadIdx.x;
    if (g < 4096) bsum1[g] = bih1[g] + bhh1[g];
    else if (g < 8192) { int j = g - 4096; bsum2[j] = bih2[j] + bhh2[j]; }
    else if (g < 8192 + kNS) {
        int t = g - 8192;
        float s = 0.f;
        for (int b = 0; b < kB; ++b) s += capmask[b * kCAP + t + 1];
        msum[t] = s;
    }
}

// ---------------- encoder GEMM: outF = A@B + bias ----------------
template <int KT>
__global__ __launch_bounds__(256) void enc_gemm(
    const unsigned short* __restrict__ Ap, const unsigned short* __restrict__ Bp,
    const float* __restrict__ bias, float* __restrict__ outF)
{
    __shared__ unsigned short Asm[3][2048];
    __shared__ unsigned short Bsm[3][2048];
    int tid = threadIdx.x, w = tid >> 6, l = tid & 63;
    int nb = blockIdx.x, mb = blockIdx.y;
    f32x4 acc[4][1] = {};
    mfma_kloop<1, KT>(Ap + (size_t)mb * KT * 2048, Bp + (size_t)nb * KT * 2048,
                      &Asm[0][0], &Bsm[0][0], w, l, acc);
    int ul = l & 15, sg = l >> 4;
    int n = nb * 64 + w * 16 + ul;
    float bv = bias[n];
#pragma unroll
    for (int ms = 0; ms < 4; ++ms)
#pragma unroll
        for (int r = 0; r < 4; ++r) {
            int row = mb * 64 + ms * 16 + sg * 4 + r;
            outF[(size_t)row * kH + n] = acc[ms][0][r] + bv;
        }
}

// ---------------- P3: feat_h -> xcat1p(+2048) and h2p ----------------
__global__ __launch_bounds__(256) void p3_gemm(
    const unsigned short* __restrict__ Ap, const unsigned short* __restrict__ Bp,
    const float* __restrict__ bias, unsigned short* __restrict__ xcat1p,
    unsigned short* __restrict__ h2p)
{
    __shared__ unsigned short Asm[3][2048];
    __shared__ unsigned short Bsm[3][2048];
    int tid = threadIdx.x, w = tid >> 6, l = tid & 63;
    int nb = blockIdx.x;
    f32x4 acc[4][1] = {};
    mfma_kloop<1, 64>(Ap, Bp + (size_t)nb * 64 * 2048, &Asm[0][0], &Bsm[0][0], w, l, acc);
    int ul = l & 15, sg = l >> 4;
    int n = nb * 64 + w * 16 + ul;
    float bv = bias[n];
#pragma unroll
    for (int ms = 0; ms < 4; ++ms)
#pragma unroll
        for (int r = 0; r < 4; ++r) {
            int row = ms * 16 + sg * 4 + r;
            unsigned short hb = f2bf(acc[ms][0][r] + bv);
            store_packedA(xcat1p, row, 2048 + n, hb);
            store_packedA(h2p, row, n, hb);
        }
}

// ---------------- hWa = h_prev @ att_Wa ----------------
__global__ __launch_bounds__(256) void hwa_gemm(
    const unsigned short* __restrict__ h2p, const unsigned short* __restrict__ WaP,
    float* __restrict__ hw)
{
    __shared__ unsigned short Asm[3][2048];
    __shared__ unsigned short Bsm[3][2048];
    int tid = threadIdx.x, w = tid >> 6, l = tid & 63;
    int nb = blockIdx.x;
    f32x4 acc[4][1] = {};
    mfma_kloop<1, 32>(h2p, WaP + (size_t)nb * 32 * 2048, &Asm[0][0], &Bsm[0][0], w, l, acc);
    int ul = l & 15, sg = l >> 4;
    int n = nb * 64 + w * 16 + ul;
#pragma unroll
    for (int ms = 0; ms < 4; ++ms)
#pragma unroll
        for (int r = 0; r < 4; ++r)
            hw[(size_t)(ms * 16 + sg * 4 + r) * kH + n] = acc[ms][0][r];
}

// ---------------- fused attention (per batch row) ----------------
__global__ __launch_bounds__(256) void attn_fused(
    const float* __restrict__ hw, const float* __restrict__ imgp,
    const float* __restrict__ attw, const float* __restrict__ vf,
    const float* __restrict__ vmask, const float* __restrict__ Wemb,
    const int* __restrict__ captions, int s, unsigned short* __restrict__ xcat1p)
{
    __shared__ float hwv[kH];
    __shared__ float es[48];
    int b = blockIdx.x, tid = threadIdx.x;
    for (int i = tid; i < kH; i += 256) hwv[i] = hw[(size_t)b * kH + i];
    __syncthreads();
    int w = tid >> 6, l = tid & 63;
    for (int t = w; t < kTV; t += 4) {
        const float* ip = imgp + ((size_t)b * kTV + t) * kH;
        float p = 0.f;
#pragma unroll
        for (int hh = 0; hh < 16; ++hh) {
            int h = hh * 64 + l;
            p += tanh_fast(hwv[h] + ip[h]) * attw[h];
        }
        for (int off = 32; off; off >>= 1) p += __shfl_down(p, off);
        if (l == 0) es[t] = p;
    }
    __syncthreads();
    float mx = -1e30f;
    for (int t = 0; t < kTV; ++t) mx = fmaxf(mx, es[t]);
    const float* vm = vmask + b * kTV;
    float den = 0.f;
    for (int t = 0; t < kTV; ++t) den += vm[t] * __expf(es[t] - mx);
    den = den + (den == 0.f ? 1.f : 0.f) + 1e-9f;
    int h0 = tid * 4;
    float4 av = {0.f, 0.f, 0.f, 0.f};
    for (int t = 0; t < kTV; ++t) {
        float wgt = vm[t] * __expf(es[t] - mx) / den;
        float4 v = *(const float4*)(vf + ((size_t)b * kTV + t) * kH + h0);
        av.x += wgt * v.x; av.y += wgt * v.y; av.z += wgt * v.z; av.w += wgt * v.w;
    }
    store_packedA(xcat1p, b, 1024 + h0 + 0, f2bf(av.x));
    store_packedA(xcat1p, b, 1024 + h0 + 1, f2bf(av.y));
    store_packedA(xcat1p, b, 1024 + h0 + 2, f2bf(av.z));
    store_packedA(xcat1p, b, 1024 + h0 + 3, f2bf(av.w));
    int word = captions[b * kCAP + s];
    float4 e4 = *(const float4*)(Wemb + (size_t)word * kH + h0);
    store_packedA(xcat1p, b, h0 + 0, f2bf(e4.x));
    store_packedA(xcat1p, b, h0 + 1, f2bf(e4.y));
    store_packedA(xcat1p, b, h0 + 2, f2bf(e4.z));
    store_packedA(xcat1p, b, h0 + 3, f2bf(e4.w));
}

// ---------------- gates GEMM + fused LSTM cell ----------------
template <int KT>
__global__ __launch_bounds__(256) void gates_cell(
    const unsigned short* __restrict__ Ap, const unsigned short* __restrict__ Bp,
    const float* __restrict__ bsum, float* __restrict__ cbuf,
    unsigned short* __restrict__ dA, int ofsA,
    unsigned short* __restrict__ dB, int ofsB)
{
    __shared__ unsigned short Asm[3][2048];
    __shared__ unsigned short Bsm[3][2048];
    __shared__ float gsm[4][64][17];
    int tid = threadIdx.x, w = tid >> 6, l = tid & 63, nb = blockIdx.x;
    f32x4 acc[4][1] = {};
    mfma_kloop<1, KT>(Ap, Bp + (size_t)nb * KT * 2048, &Asm[0][0], &Bsm[0][0], w, l, acc);
    int ul = l & 15, sg = l >> 4;
    float bv = bsum[w * 1024 + nb * 16 + ul];
#pragma unroll
    for (int ms = 0; ms < 4; ++ms)
#pragma unroll
        for (int r = 0; r < 4; ++r)
            gsm[w][ms * 16 + sg * 4 + r][ul] = acc[ms][0][r] + bv;
    __syncthreads();
#pragma unroll
    for (int q = 0; q < 4; ++q) {
        int idx = tid * 4 + q;
        int row = idx >> 4, uc = idx & 15, u = nb * 16 + uc;
        float gi = gsm[0][row][uc], gf = gsm[1][row][uc];
        float gg = gsm[2][row][uc], go = gsm[3][row][uc];
        float c = sigm(gf) * cbuf[(size_t)row * kH + u] + sigm(gi) * tanh_fast(gg);
        cbuf[(size_t)row * kH + u] = c;
        unsigned short hb = f2bf(sigm(go) * tanh_fast(c));
        store_packedA(dA, row, ofsA + u, hb);
        store_packedA(dB, row, ofsB + u, hb);
    }
}

// ---------------- logits GEMM + per-block exp-sum (no max needed) ----------------
__global__ __launch_bounds__(256) void logits_k(
    const unsigned short* __restrict__ h2p, const unsigned short* __restrict__ WvP,
    const float* __restrict__ embb, const int* __restrict__ captions, int s,
    float* __restrict__ psumP, float* __restrict__ tlogs)
{
    __shared__ unsigned short Asm[3][2048];
    __shared__ unsigned short Bsm[3][4096];
    __shared__ float rsum[4][64];
    __shared__ int stgt[64];
    int tid = threadIdx.x, w = tid >> 6, l = tid & 63, nb = blockIdx.x;
    if (tid < 64) stgt[tid] = captions[tid * kCAP + s + 1];
    f32x4 acc[4][2] = {};
    mfma_kloop<2, 32>(h2p, WvP + (size_t)nb * 32 * 4096, &Asm[0][0], &Bsm[0][0], w, l, acc);
    int ul = l & 15, sg = l >> 4;
    int n0 = nb * 128 + (2 * w + 0) * 16 + ul;
    int n1 = nb * 128 + (2 * w + 1) * 16 + ul;
    float b0 = embb[n0], b1 = embb[n1];
    float ls[4][4];
#pragma unroll
    for (int ms = 0; ms < 4; ++ms)
#pragma unroll
        for (int r = 0; r < 4; ++r) {
            int row = ms * 16 + sg * 4 + r;
            float v0 = acc[ms][0][r] + b0, v1 = acc[ms][1][r] + b1;
            ls[ms][r] = __expf(v0) + __expf(v1);
            if (n0 == stgt[row]) tlogs[s * 64 + row] = v0;
            if (n1 == stgt[row]) tlogs[s * 64 + row] = v1;
        }
#pragma unroll
    for (int m = 1; m < 16; m <<= 1)
#pragma unroll
        for (int ms = 0; ms < 4; ++ms)
#pragma unroll
            for (int r = 0; r < 4; ++r)
                ls[ms][r] += __shfl_xor(ls[ms][r], m);
    if (ul == 0)
#pragma unroll
        for (int ms = 0; ms < 4; ++ms)
#pragma unroll
            for (int r = 0; r < 4; ++r)
                rsum[w][ms * 16 + sg * 4 + r] = ls[ms][r];
    __syncthreads();
    if (tid < 64)
        psumP[((size_t)s * 250 + nb) * 64 + tid] =
            rsum[0][tid] + rsum[1][tid] + rsum[2][tid] + rsum[3][tid];
}

// ---------------- final loss over all steps ----------------
__global__ __launch_bounds__(256) void final_loss(
    const float* __restrict__ psumP, const float* __restrict__ tlogs,
    const float* __restrict__ msum, float* __restrict__ out)
{
    __shared__ float sl[16000];
    int s = blockIdx.x, tid = threadIdx.x;
    const float* src = psumP + (size_t)s * 16000;
    for (int i = tid; i < 16000; i += 256) sl[i] = src[i];
    __syncthreads();
    if (tid < 64) {
        float tot = 0.f;
        for (int i = 0; i < 250; ++i) tot += sl[i * 64 + tid];
        float logp = tlogs[s * 64 + tid] - __logf(tot);
        float term = -logp * msum[s] * (1.f / 4096.f);
        for (int off = 32; off; off >>= 1) term += __shfl_down(term, off);
        if (tid == 0) atomicAdd(out, term);
    }
}

// ---------------- host ----------------
extern "C" void kernel_launch(void* const* d_in, const int* in_sizes, int n_in,
                              void* d_out, int out_size, void* d_ws, size_t ws_size,
                              hipStream_t stream)
{
    const float* action_feat = (const float*)d_in[1];
    const float* video_mask  = (const float*)d_in[3];
    const int*   captions    = (const int*)d_in[4];
    const float* capmask     = (const float*)d_in[5];
    const float* enc_img_W   = (const float*)d_in[6];
    const float* enc_img_b   = (const float*)d_in[7];
    const float* enc_mean_W  = (const float*)d_in[8];
    const float* enc_mean_b  = (const float*)d_in[9];
    const float* att_w       = (const float*)d_in[10];
    const float* att_Wa      = (const float*)d_in[11];
    const float* att_Ua      = (const float*)d_in[12];
    const float* att_ba      = (const float*)d_in[13];
    const float* Wemb        = (const float*)d_in[14];
    const float* embW        = (const float*)d_in[15];
    const float* embb        = (const float*)d_in[16];
    const float* W1ih        = (const float*)d_in[17];
    const float* W1hh        = (const float*)d_in[18];
    const float* b1ih        = (const float*)d_in[19];
    const float* b1hh        = (const float*)d_in[20];
    const float* W2ih        = (const float*)d_in[21];
    const float* W2hh        = (const float*)d_in[22];
    const float* b2ih        = (const float*)d_in[23];
    const float* b2hh        = (const float*)d_in[24];

    char* base = (char*)d_ws;
    size_t off = 0;
    auto alloc = [&](size_t bytes) {
        char* p = base + off;
        off = (off + bytes + 255) & ~(size_t)255;
        return p;
    };
    constexpr int BIG = 0x40000000;

    float* vf    = (float*)alloc((size_t)2560 * 1024 * 4);
    float* imgp  = (float*)alloc((size_t)2560 * 1024 * 4);
    float* fm    = (float*)alloc((size_t)64 * 2048 * 4);
    float* hw    = (float*)alloc((size_t)64 * 1024 * 4);
    float* bsum1 = (float*)alloc(4096 * 4);
    float* bsum2 = (float*)alloc(4096 * 4);
    float* msum  = (float*)alloc(32 * 4);
    float* psumP = (float*)alloc((size_t)kNS * 250 * 64 * 4);
    float* tlogs = (float*)alloc((size_t)kNS * 64 * 4);
    // zero-init block: xcat2p[2], c1, c2 contiguous
    unsigned short* x2p0 = (unsigned short*)alloc((size_t)64 * 2048 * 2);
    unsigned short* x2p1 = (unsigned short*)alloc((size_t)64 * 2048 * 2);
    float* c1    = (float*)alloc((size_t)64 * 1024 * 4);
    float* c2    = (float*)alloc((size_t)64 * 1024 * 4);
    size_t zlen  = (size_t)((char*)(c2 + 64 * 1024) - (char*)x2p0);

    unsigned short* x1p0 = (unsigned short*)alloc((size_t)64 * 3072 * 2);
    unsigned short* x1p1 = (unsigned short*)alloc((size_t)64 * 3072 * 2);
    unsigned short* h2p  = (unsigned short*)alloc((size_t)64 * 1024 * 2);
    unsigned short* afP  = (unsigned short*)alloc((size_t)2560 * 2048 * 2);
    unsigned short* vfP  = (unsigned short*)alloc((size_t)2560 * 1024 * 2);
    unsigned short* fmP  = (unsigned short*)alloc((size_t)64 * 2048 * 2);
    unsigned short* WiP  = (unsigned short*)alloc((size_t)2048 * 1024 * 2);
    unsigned short* WmP  = (unsigned short*)alloc((size_t)2048 * 1024 * 2);
    unsigned short* WuaP = (unsigned short*)alloc((size_t)1024 * 1024 * 2);
    unsigned short* WaP  = (unsigned short*)alloc((size_t)1024 * 1024 * 2);
    unsigned short* W1p  = (unsigned short*)alloc((size_t)3072 * 4096 * 2);
    unsigned short* W2p  = (unsigned short*)alloc((size_t)2048 * 4096 * 2);
    unsigned short* WvP  = (unsigned short*)alloc((size_t)1024 * 32000 * 2);
    if (off > ws_size) return;

    hipMemsetAsync(d_out, 0, 4, stream);
    hipMemsetAsync(x2p0, 0, zlen, stream);

    prep_kernel<<<33, 256, 0, stream>>>(b1ih, b1hh, b2ih, b2hh, capmask,
                                        bsum1, bsum2, msum);
    mean_f<<<64, 256, 0, stream>>>(action_feat, fm);
    pack_rm<<<dim3(16, 4), 256, 0, stream>>>(fm, 2048, BIG, nullptr, 0,
                                             4, 16, 64, 64, fmP);
    pack_rm<<<dim3(16, 160), 256, 0, stream>>>(action_feat, 2048, BIG, nullptr, 0,
                                               4, 16, 64, 64, afP);
    pack_rm<<<dim3(24, 256), 256, 0, stream>>>(W1ih, 2048, 2048, W1hh, 1024,
                                               4, 1024, 16, 96, W1p);
    pack_rm<<<dim3(16, 256), 256, 0, stream>>>(W2ih, 1024, 1024, W2hh, 1024,
                                               4, 1024, 16, 64, W2p);
    pack_kn<<<1024, 256, 0, stream>>>(enc_img_W, WiP, 2048, 1024, 4);
    pack_kn<<<1024, 256, 0, stream>>>(enc_mean_W, WmP, 2048, 1024, 4);
    pack_kn<<<512, 256, 0, stream>>>(att_Ua, WuaP, 1024, 1024, 4);
    pack_kn<<<512, 256, 0, stream>>>(att_Wa, WaP, 1024, 1024, 4);
    pack_cm<<<dim3(250, 32), 256, 0, stream>>>(embW, WvP);

    enc_gemm<64><<<dim3(16, 40), 256, 0, stream>>>(afP, WiP, enc_img_b, vf);
    pack_rm<<<dim3(8, 160), 256, 0, stream>>>(vf, 1024, BIG, nullptr, 0,
                                              4, 16, 64, 32, vfP);
    p3_gemm<<<16, 256, 0, stream>>>(fmP, WmP, enc_mean_b, x1p0, h2p);
    enc_gemm<32><<<dim3(16, 40), 256, 0, stream>>>(vfP, WuaP, att_ba, imgp);

    for (int s = 0; s < kNS; ++s) {
        unsigned short* x1c = (s & 1) ? x1p1 : x1p0;
        unsigned short* x1n = (s & 1) ? x1p0 : x1p1;
        unsigned short* x2c = (s & 1) ? x2p1 : x2p0;
        unsigned short* x2n = (s & 1) ? x2p0 : x2p1;
        hwa_gemm<<<16, 256, 0, stream>>>(h2p, WaP, hw);
        attn_fused<<<64, 256, 0, stream>>>(hw, imgp, att_w, vf, video_mask,
                                           Wemb, captions, s, x1c);
        gates_cell<96><<<64, 256, 0, stream>>>(x1c, W1p, bsum1, c1,
                                               x1n, 2048, x2c, 0);
        gates_cell<64><<<64, 256, 0, stream>>>(x2c, W2p, bsum2, c2,
                                               x2n, 1024, h2p, 0);
        logits_k<<<250, 256, 0, stream>>>(h2p, WvP, embb, captions, s,
                                          psumP, tlogs);
    }
    final_loss<<<kNS, 256, 0, stream>>>(psumP, tlogs, msum, (float*)d_out);
}